// Round 11
// baseline (203.430 us; speedup 1.0000x reference)
//
#include <hip/hip_runtime.h>
#include <hip/hip_bf16.h>

typedef __hip_bfloat16 bf16h;
typedef short short8 __attribute__((ext_vector_type(8)));
typedef float floatx4 __attribute__((ext_vector_type(4)));

__device__ __forceinline__ float bfu2f(unsigned int u) {
    return __uint_as_float((u & 0xffffu) << 16);
}
__device__ __forceinline__ float bfhi2f(unsigned int u) {
    return __uint_as_float(u & 0xffff0000u);
}
__device__ __forceinline__ unsigned short f2bfu(float f) {
    bf16h b = __float2bfloat16(f);  // RNE
    return *(unsigned short*)&b;
}

#define SLOTS 64
#define PREP_BLOCKS 1024

// ---------------- merged build kernel: countfill role + prep role ----------------
// R11: prep and countfill are independent; countfill blocks early-exit on 7/8 of
// edges (XCD dst-partition), so prep's streaming work backfills the freed slots.
// Blocks [0, ecx): single-pass fixed-slot CSR build, XCD dst-partitioned
//   (blockIdx&7 ~ XCD, m09 round-robin: each dst-range's cnt/slots lines written by
//    exactly ONE XCD -> L2-resident, single writeback. R3 lesson: unpartitioned
//    scattered 4B writes ping-pong lines across 8 L2s -> 3x slower.)
// Blocks [ecx, ecx+PREP_BLOCKS): detect x dtype, W -> MFMA bf16 hi/lo fragments,
//   bias fp32, x -> UNSCALED bf16 gather table.
// cnt zeroing moved to hipMemsetAsync (capture-safe) so countfill can start at once.
__global__ __launch_bounds__(256) void k_build(const int* __restrict__ ei,
                                               int* __restrict__ cnt,
                                               int* __restrict__ slots,
                                               const void* __restrict__ x,
                                               const void* __restrict__ W1, const void* __restrict__ b1,
                                               const void* __restrict__ W2, const void* __restrict__ b2,
                                               unsigned short* __restrict__ W1h, unsigned short* __restrict__ W1l,
                                               unsigned short* __restrict__ W2h, unsigned short* __restrict__ W2l,
                                               float* __restrict__ bfv1, float* __restrict__ bfv2,
                                               unsigned int* __restrict__ Xb,
                                               int e, int n, int rpx, int ecx) {
    int t = threadIdx.x;
    if ((int)blockIdx.x < ecx) {
        // ---- countfill role ----
        __shared__ int sSt;
        if (t < 64) {  // int64 edges => odd words all zero
            int v = ei[2 * t + 1];
            unsigned long long b = __ballot(v == 0);
            if (t == 0) sSt = (b == ~0ull) ? 2 : 1;
        }
        __syncthreads();
        int st = sSt;
        int xcd = blockIdx.x & 7;
        int i = ((int)blockIdx.x >> 3) * 256 + t;
        if (i >= e) return;
        int d = ei[(size_t)e * st + (size_t)i * st];
        int lo = xcd * rpx, hi = min(n, lo + rpx);
        if (d < lo || d >= hi) return;
        int s = ei[(size_t)i * st];
        if (s < 0 || s >= n) return;
        int pos = atomicAdd(&cnt[d], 1);
        if (pos < SLOTS) slots[(size_t)d * SLOTS + pos] = s;
    } else {
        // ---- prep role ----
        __shared__ int sIsB;
        if (t < 64) {  // per-block local bf16-vs-fp32 detection on x
            unsigned int w = ((const unsigned int*)x)[t];
            unsigned int ef = (w >> 7) & 0xFFu;
            unsigned long long b = __ballot(ef >= 0x76u && ef <= 0x82u);
            if (t == 0) sIsB = (__popcll(b) >= 40) ? 1 : 0;
        }
        __syncthreads();
        bool isb = sIsB != 0;

        int gsz = PREP_BLOCKS * 256;
        int gid = ((int)blockIdx.x - ecx) * 256 + t;
        for (int i = gid; i < 16384; i += gsz) {
            int c  = i >> 11;
            int kk = (i >> 9) & 3;
            int ln = (i >> 3) & 63;
            int j  = i & 7;
            int k    = kk * 32 + (ln >> 4) * 8 + j;
            int ncol = c * 16 + (ln & 15);
            int src  = k * 128 + ncol;
            float v1 = isb ? bfu2f(((const unsigned short*)W1)[src]) : ((const float*)W1)[src];
            float v2 = isb ? bfu2f(((const unsigned short*)W2)[src]) : ((const float*)W2)[src];
            unsigned short h1 = f2bfu(v1), h2 = f2bfu(v2);
            W1h[i] = h1; W1l[i] = f2bfu(v1 - bfu2f(h1));
            W2h[i] = h2; W2l[i] = f2bfu(v2 - bfu2f(h2));
        }
        if (gid < 128) {
            bfv1[gid] = isb ? bfu2f(((const unsigned short*)b1)[gid]) : ((const float*)b1)[gid];
            bfv2[gid] = isb ? bfu2f(((const unsigned short*)b2)[gid]) : ((const float*)b2)[gid];
        }
        int total = n * 64;  // packed bf16 pairs, unscaled
        if (isb) {
            const unsigned int* xs = (const unsigned int*)x;
            for (int i = gid; i < total; i += gsz) Xb[i] = xs[i];
        } else {
            const float2* xf = (const float2*)x;
            for (int i = gid; i < total; i += gsz) {
                float2 v = xf[i];
                Xb[i] = ((unsigned int)f2bfu(v.y) << 16) | f2bfu(v.x);
            }
        }
    }
}

// dinv[i] = rsqrtf(cnt[i]+1) once, instead of per-edge recompute. Bit-identical values.
__global__ __launch_bounds__(256) void k_dinv(const int* __restrict__ cnt,
                                              float* __restrict__ dinv, int n) {
    int i = blockIdx.x * 256 + threadIdx.x;
    if (i < n) dinv[i] = rsqrtf((float)cnt[i] + 1.0f);
}

// ---------------- fused aggregate + MFMA GEMM ----------------
// Block = 256 thr (4 waves), 16 nodes: each 16-lane group owns exactly ONE node.
// R10: 3125-block grid (12500 waves ~ 49/CU demanded) keeps resident waves at cap
// while blocks drain. Inner loop is the proven R5 shape (8-edge unroll, dual-int4
// slot prefetch, dinv table, hoisted self-row; ~45 VGPR, <=64 tier). R6/R7 lessons:
// don't deepen per-lane MLP (VGPR tier cliff), don't pin launch bounds (spill).
template <bool OUT_BF16>
__global__ __launch_bounds__(256) void k_fused(const unsigned int* __restrict__ Xt,
                                               const int* __restrict__ cnt,
                                               const float* __restrict__ dinv,
                                               const int* __restrict__ slots,
                                               const unsigned short* __restrict__ Wh,
                                               const unsigned short* __restrict__ Wl,
                                               const float* __restrict__ bias,
                                               void* __restrict__ out, int n) {
    __shared__ float sA[16][132];  // +4 pad
    int t = threadIdx.x;
    int wv = t >> 6, lane = t & 63;
    int g = lane >> 4, l = lane & 15;
    int col = l * 4;  // uint index: 16 lanes x uint4 = full 128-feature row
    int rowBase = blockIdx.x * 16;
    int nm1 = n - 1;
    int grp = wv * 4 + g;  // 0..15 — this group's node

    // ---- phase 1: group grp aggregates node rowBase + grp ----
    {
        int node = rowBase + grp;
        int nodeC = min(node, nm1);
        int end = (node < n) ? min(cnt[nodeC], SLOTS) : 0;
        const int* sl = slots + (size_t)nodeC * SLOTS;
        // hoisted independent loads: self dinv + self row (consumed after the loop)
        float wd = dinv[nodeC];
        uint4 vself = *(const uint4*)(Xt + (unsigned)(nodeC * 64 + col));
        float acc[8] = {0.f, 0.f, 0.f, 0.f, 0.f, 0.f, 0.f, 0.f};
        int4 sva = *(const int4*)(sl);      // 64-slot rows: always in-bounds
        int4 svb = *(const int4*)(sl + 4);
        for (int j = 0; j < end; j += 8) {
            int4 ca = sva, cb = svb;
            if (j + 8 < end) {  // prefetch next oct before row loads
                sva = *(const int4*)(sl + j + 8);
                svb = *(const int4*)(sl + j + 12);
            }
            int ss[8] = {ca.x, ca.y, ca.z, ca.w, cb.x, cb.y, cb.z, cb.w};
#pragma unroll
            for (int k = 0; k < 8; ++k) {
                bool ok = (j + k) < end;
                int s = ok ? ss[k] : nodeC;  // padded lanes hit hot self row, w=0
                float w = ok ? dinv[s] : 0.f;
                uint4 v = *(const uint4*)(Xt + (unsigned)(s * 64 + col));
                acc[0] += w * bfu2f(v.x);  acc[1] += w * bfhi2f(v.x);
                acc[2] += w * bfu2f(v.y);  acc[3] += w * bfhi2f(v.y);
                acc[4] += w * bfu2f(v.z);  acc[5] += w * bfhi2f(v.z);
                acc[6] += w * bfu2f(v.w);  acc[7] += w * bfhi2f(v.w);
            }
        }
        {
            acc[0] += wd * bfu2f(vself.x);  acc[1] += wd * bfhi2f(vself.x);
            acc[2] += wd * bfu2f(vself.y);  acc[3] += wd * bfhi2f(vself.y);
            acc[4] += wd * bfu2f(vself.z);  acc[5] += wd * bfhi2f(vself.z);
            acc[6] += wd * bfu2f(vself.w);  acc[7] += wd * bfhi2f(vself.w);
            float* po = &sA[grp][l * 8];
#pragma unroll
            for (int q = 0; q < 8; ++q) po[q] = wd * acc[q];
        }
    }
    __syncthreads();

    // ---- phase 2: one 16-row tile; wave wv does column-blocks {2wv, 2wv+1} ----
    {
        floatx4 acc2[2];
        acc2[0] = (floatx4){0.f, 0.f, 0.f, 0.f};
        acc2[1] = (floatx4){0.f, 0.f, 0.f, 0.f};

#pragma unroll
        for (int kk = 0; kk < 4; ++kk) {
            const float* ap = &sA[l][kk * 32 + g * 8];  // row=l16, k-seg=quad
            float av[8];
#pragma unroll
            for (int j2 = 0; j2 < 8; ++j2) av[j2] = ap[j2];
            short8 ah, alo;
#pragma unroll
            for (int j2 = 0; j2 < 8; ++j2) {
                unsigned short h = f2bfu(av[j2]);
                ah[j2]  = (short)h;
                alo[j2] = (short)f2bfu(av[j2] - bfu2f(h));
            }
#pragma unroll
            for (int cc = 0; cc < 2; ++cc) {
                int c = wv * 2 + cc;
                int fo = ((c * 4 + kk) * 64 + lane) * 8;
                short8 bh = *(const short8*)(Wh + fo);
                short8 bl = *(const short8*)(Wl + fo);
                acc2[cc] = __builtin_amdgcn_mfma_f32_16x16x32_bf16(ah, bh, acc2[cc], 0, 0, 0);
                acc2[cc] = __builtin_amdgcn_mfma_f32_16x16x32_bf16(alo, bh, acc2[cc], 0, 0, 0);
                acc2[cc] = __builtin_amdgcn_mfma_f32_16x16x32_bf16(ah, bl, acc2[cc], 0, 0, 0);
            }
        }

        // epilogue: C/D layout col = lane&15, row = quad*4 + reg  [m89-verified]
#pragma unroll
        for (int cc = 0; cc < 2; ++cc) {
            int c = wv * 2 + cc;
            int ncol = c * 16 + l;
            float bv = bias[ncol];
#pragma unroll
            for (int r = 0; r < 4; ++r) {
                int row = rowBase + g * 4 + r;
                if (row < n) {
                    float o = fmaxf(acc2[cc][r] + bv, 0.f);
                    if constexpr (OUT_BF16) {
                        ((unsigned short*)out)[(size_t)row * 128 + ncol] = f2bfu(o);
                    } else {
                        ((float*)out)[(size_t)row * 128 + ncol] = o;
                    }
                }
            }
        }
    }
}

extern "C" void kernel_launch(void* const* d_in, const int* in_sizes, int n_in,
                              void* d_out, int out_size, void* d_ws, size_t ws_size,
                              hipStream_t stream) {
    const int n = in_sizes[0] / 128;
    const int e = in_sizes[1] / 2;
    const void* x = d_in[0];
    const int* ei = (const int*)d_in[1];

    char* w = (char*)d_ws;
    size_t o = 0;
    auto alloc = [&](size_t bytes) -> char* {
        char* p = w + o;
        o += (bytes + 255) & ~(size_t)255;
        return p;
    };
    int* cnt   = (int*)alloc((size_t)n * 4);
    float* dinv = (float*)alloc((size_t)n * 4);
    int* slots = (int*)alloc((size_t)n * SLOTS * 4 + 64);  // +pad for prefetch tail
    unsigned short* W1h = (unsigned short*)alloc(16384 * 2);
    unsigned short* W1l = (unsigned short*)alloc(16384 * 2);
    unsigned short* W2h = (unsigned short*)alloc(16384 * 2);
    unsigned short* W2l = (unsigned short*)alloc(16384 * 2);
    float* bf1 = (float*)alloc(128 * 4);
    float* bf2 = (float*)alloc(128 * 4);
    unsigned int* Xb  = (unsigned int*)alloc((size_t)n * 64 * 4);  // layer-1 gather table
    unsigned int* Xb2 = (unsigned int*)alloc((size_t)n * 64 * 4);  // layer-2 gather table
    (void)ws_size;  // ~39 MB

    // zero cnt up front (capture-safe async memset) so countfill can start immediately
    hipMemsetAsync(cnt, 0, (size_t)n * 4, stream);

    const int rpx = (n + 7) / 8;           // dst-range per XCD
    int ecx = ((e + 255) / 256) * 8;       // 8 range-blocks per edge chunk
    // merged prep || countfill (independent work; prep backfills early-exited slots)
    k_build<<<ecx + PREP_BLOCKS, 256, 0, stream>>>(ei, cnt, slots,
                                                   x, d_in[2], d_in[3], d_in[4], d_in[5],
                                                   W1h, W1l, W2h, W2l, bf1, bf2, Xb,
                                                   e, n, rpx, ecx);
    k_dinv<<<(n + 255) / 256, 256, 0, stream>>>(cnt, dinv, n);

    int gf = (n + 15) / 16;  // 3125 blocks x 4 waves = 12500 waves — keeps CUs saturated
    // layer 1: Xb2 = bf16(relu((dinv*agg(dinv*Xb)) @ W1 + b1))
    k_fused<true><<<gf, 256, 0, stream>>>(Xb, cnt, dinv, slots, W1h, W1l, bf1, Xb2, n);
    // layer 2: d_out = fp32(relu((dinv*agg(dinv*Xb2)) @ W2 + b2))
    k_fused<false><<<gf, 256, 0, stream>>>(Xb2, cnt, dinv, slots, W2h, W2l, bf2, d_out, n);
}

// Round 12
// 200.883 us; speedup vs baseline: 1.0127x; 1.0127x over previous
//
#include <hip/hip_runtime.h>
#include <hip/hip_bf16.h>

typedef __hip_bfloat16 bf16h;
typedef short short8 __attribute__((ext_vector_type(8)));
typedef float floatx4 __attribute__((ext_vector_type(4)));

__device__ __forceinline__ float bfu2f(unsigned int u) {
    return __uint_as_float((u & 0xffffu) << 16);
}
__device__ __forceinline__ float bfhi2f(unsigned int u) {
    return __uint_as_float(u & 0xffff0000u);
}
__device__ __forceinline__ unsigned short f2bfu(float f) {
    bf16h b = __float2bfloat16(f);  // RNE
    return *(unsigned short*)&b;
}

#define SLOTS 64

// ---------------- prep: detect x dtype, zero cnt, W -> MFMA bf16 hi/lo fragments,
//                  bias fp32, x -> UNSCALED bf16 gather table ----
// R11 lesson: do NOT merge this with countfill — shared regalloc (VGPR collapsed to
// 12, prep starved) and Xb streaming evicts countfill's L2-resident slot lines
// (WRITE 28->44 MB). Separate kernels are faster than the "overlapped" merge.
__global__ __launch_bounds__(256) void k_prep(const void* __restrict__ x,
                                              const void* __restrict__ W1, const void* __restrict__ b1,
                                              const void* __restrict__ W2, const void* __restrict__ b2,
                                              int* __restrict__ cnt,
                                              unsigned short* __restrict__ W1h, unsigned short* __restrict__ W1l,
                                              unsigned short* __restrict__ W2h, unsigned short* __restrict__ W2l,
                                              float* __restrict__ bfv1, float* __restrict__ bfv2,
                                              unsigned int* __restrict__ Xb, int n) {
    int t = threadIdx.x;
    __shared__ int sIsB;
    if (t < 64) {  // per-block local bf16-vs-fp32 detection on x
        unsigned int w = ((const unsigned int*)x)[t];
        unsigned int ef = (w >> 7) & 0xFFu;
        unsigned long long b = __ballot(ef >= 0x76u && ef <= 0x82u);
        if (t == 0) sIsB = (__popcll(b) >= 40) ? 1 : 0;
    }
    __syncthreads();
    bool isb = sIsB != 0;

    int gsz = gridDim.x * 256;
    int gid = blockIdx.x * 256 + t;
    for (int i = gid; i < n; i += gsz) cnt[i] = 0;
    for (int i = gid; i < 16384; i += gsz) {
        int c  = i >> 11;
        int kk = (i >> 9) & 3;
        int ln = (i >> 3) & 63;
        int j  = i & 7;
        int k    = kk * 32 + (ln >> 4) * 8 + j;
        int ncol = c * 16 + (ln & 15);
        int src  = k * 128 + ncol;
        float v1 = isb ? bfu2f(((const unsigned short*)W1)[src]) : ((const float*)W1)[src];
        float v2 = isb ? bfu2f(((const unsigned short*)W2)[src]) : ((const float*)W2)[src];
        unsigned short h1 = f2bfu(v1), h2 = f2bfu(v2);
        W1h[i] = h1; W1l[i] = f2bfu(v1 - bfu2f(h1));
        W2h[i] = h2; W2l[i] = f2bfu(v2 - bfu2f(h2));
    }
    if (gid < 128) {
        bfv1[gid] = isb ? bfu2f(((const unsigned short*)b1)[gid]) : ((const float*)b1)[gid];
        bfv2[gid] = isb ? bfu2f(((const unsigned short*)b2)[gid]) : ((const float*)b2)[gid];
    }
    int total = n * 64;  // packed bf16 pairs, unscaled
    if (isb) {
        const unsigned int* xs = (const unsigned int*)x;
        for (int i = gid; i < total; i += gsz) Xb[i] = xs[i];
    } else {
        const float2* xf = (const float2*)x;
        for (int i = gid; i < total; i += gsz) {
            float2 v = xf[i];
            Xb[i] = ((unsigned int)f2bfu(v.y) << 16) | f2bfu(v.x);
        }
    }
}

// ---------------- single-pass fixed-slot CSR build, XCD dst-partitioned ----------------
// blockIdx&7 ~ XCD (round-robin dispatch, m09): each dst-range's cnt/slots lines are
// written by exactly ONE XCD -> lines stay resident in that L2, single writeback.
// (R3 lesson: unpartitioned scattered 4B writes ping-pong lines across 8 L2s.)
__global__ __launch_bounds__(256) void k_countfill(const int* __restrict__ ei,
                                                   int* __restrict__ cnt,
                                                   int* __restrict__ slots,
                                                   int e, int n, int rpx) {
    __shared__ int sSt;
    int t = threadIdx.x;
    if (t < 64) {  // int64 edges => odd words all zero
        int v = ei[2 * t + 1];
        unsigned long long b = __ballot(v == 0);
        if (t == 0) sSt = (b == ~0ull) ? 2 : 1;
    }
    __syncthreads();
    int st = sSt;
    int xcd = blockIdx.x & 7;
    int i = (blockIdx.x >> 3) * 256 + t;
    if (i >= e) return;
    int d = ei[(size_t)e * st + (size_t)i * st];
    int lo = xcd * rpx, hi = min(n, lo + rpx);
    if (d < lo || d >= hi) return;
    int s = ei[(size_t)i * st];
    if (s < 0 || s >= n) return;
    int pos = atomicAdd(&cnt[d], 1);
    if (pos < SLOTS) slots[(size_t)d * SLOTS + pos] = s;
}

// dinv[i] = rsqrtf(cnt[i]+1) once, instead of per-edge recompute. Bit-identical values.
__global__ __launch_bounds__(256) void k_dinv(const int* __restrict__ cnt,
                                              float* __restrict__ dinv, int n) {
    int i = blockIdx.x * 256 + threadIdx.x;
    if (i < n) dinv[i] = rsqrtf((float)cnt[i] + 1.0f);
}

// ---------------- fused aggregate + MFMA GEMM ----------------
// Block = 256 thr (4 waves), 16 nodes: each 16-lane group owns exactly ONE node.
// R10: 3125-block grid (12500 waves ~ 49/CU demanded) keeps resident waves at cap
// while blocks drain. Inner loop is the proven R5 shape (8-edge unroll, dual-int4
// slot prefetch, dinv table, hoisted self-row; ~45 VGPR, <=64 tier). R6/R7 lessons:
// don't deepen per-lane MLP (VGPR tier cliff), don't pin launch bounds (spill).
template <bool OUT_BF16>
__global__ __launch_bounds__(256) void k_fused(const unsigned int* __restrict__ Xt,
                                               const int* __restrict__ cnt,
                                               const float* __restrict__ dinv,
                                               const int* __restrict__ slots,
                                               const unsigned short* __restrict__ Wh,
                                               const unsigned short* __restrict__ Wl,
                                               const float* __restrict__ bias,
                                               void* __restrict__ out, int n) {
    __shared__ float sA[16][132];  // +4 pad
    int t = threadIdx.x;
    int wv = t >> 6, lane = t & 63;
    int g = lane >> 4, l = lane & 15;
    int col = l * 4;  // uint index: 16 lanes x uint4 = full 128-feature row
    int rowBase = blockIdx.x * 16;
    int nm1 = n - 1;
    int grp = wv * 4 + g;  // 0..15 — this group's node

    // ---- phase 1: group grp aggregates node rowBase + grp ----
    {
        int node = rowBase + grp;
        int nodeC = min(node, nm1);
        int end = (node < n) ? min(cnt[nodeC], SLOTS) : 0;
        const int* sl = slots + (size_t)nodeC * SLOTS;
        // hoisted independent loads: self dinv + self row (consumed after the loop)
        float wd = dinv[nodeC];
        uint4 vself = *(const uint4*)(Xt + (unsigned)(nodeC * 64 + col));
        float acc[8] = {0.f, 0.f, 0.f, 0.f, 0.f, 0.f, 0.f, 0.f};
        int4 sva = *(const int4*)(sl);      // 64-slot rows: always in-bounds
        int4 svb = *(const int4*)(sl + 4);
        for (int j = 0; j < end; j += 8) {
            int4 ca = sva, cb = svb;
            if (j + 8 < end) {  // prefetch next oct before row loads
                sva = *(const int4*)(sl + j + 8);
                svb = *(const int4*)(sl + j + 12);
            }
            int ss[8] = {ca.x, ca.y, ca.z, ca.w, cb.x, cb.y, cb.z, cb.w};
#pragma unroll
            for (int k = 0; k < 8; ++k) {
                bool ok = (j + k) < end;
                int s = ok ? ss[k] : nodeC;  // padded lanes hit hot self row, w=0
                float w = ok ? dinv[s] : 0.f;
                uint4 v = *(const uint4*)(Xt + (unsigned)(s * 64 + col));
                acc[0] += w * bfu2f(v.x);  acc[1] += w * bfhi2f(v.x);
                acc[2] += w * bfu2f(v.y);  acc[3] += w * bfhi2f(v.y);
                acc[4] += w * bfu2f(v.z);  acc[5] += w * bfhi2f(v.z);
                acc[6] += w * bfu2f(v.w);  acc[7] += w * bfhi2f(v.w);
            }
        }
        {
            acc[0] += wd * bfu2f(vself.x);  acc[1] += wd * bfhi2f(vself.x);
            acc[2] += wd * bfu2f(vself.y);  acc[3] += wd * bfhi2f(vself.y);
            acc[4] += wd * bfu2f(vself.z);  acc[5] += wd * bfhi2f(vself.z);
            acc[6] += wd * bfu2f(vself.w);  acc[7] += wd * bfhi2f(vself.w);
            float* po = &sA[grp][l * 8];
#pragma unroll
            for (int q = 0; q < 8; ++q) po[q] = wd * acc[q];
        }
    }
    __syncthreads();

    // ---- phase 2: one 16-row tile; wave wv does column-blocks {2wv, 2wv+1} ----
    {
        floatx4 acc2[2];
        acc2[0] = (floatx4){0.f, 0.f, 0.f, 0.f};
        acc2[1] = (floatx4){0.f, 0.f, 0.f, 0.f};

#pragma unroll
        for (int kk = 0; kk < 4; ++kk) {
            const float* ap = &sA[l][kk * 32 + g * 8];  // row=l16, k-seg=quad
            float av[8];
#pragma unroll
            for (int j2 = 0; j2 < 8; ++j2) av[j2] = ap[j2];
            short8 ah, alo;
#pragma unroll
            for (int j2 = 0; j2 < 8; ++j2) {
                unsigned short h = f2bfu(av[j2]);
                ah[j2]  = (short)h;
                alo[j2] = (short)f2bfu(av[j2] - bfu2f(h));
            }
#pragma unroll
            for (int cc = 0; cc < 2; ++cc) {
                int c = wv * 2 + cc;
                int fo = ((c * 4 + kk) * 64 + lane) * 8;
                short8 bh = *(const short8*)(Wh + fo);
                short8 bl = *(const short8*)(Wl + fo);
                acc2[cc] = __builtin_amdgcn_mfma_f32_16x16x32_bf16(ah, bh, acc2[cc], 0, 0, 0);
                acc2[cc] = __builtin_amdgcn_mfma_f32_16x16x32_bf16(alo, bh, acc2[cc], 0, 0, 0);
                acc2[cc] = __builtin_amdgcn_mfma_f32_16x16x32_bf16(ah, bl, acc2[cc], 0, 0, 0);
            }
        }

        // epilogue: C/D layout col = lane&15, row = quad*4 + reg  [m89-verified]
#pragma unroll
        for (int cc = 0; cc < 2; ++cc) {
            int c = wv * 2 + cc;
            int ncol = c * 16 + l;
            float bv = bias[ncol];
#pragma unroll
            for (int r = 0; r < 4; ++r) {
                int row = rowBase + g * 4 + r;
                if (row < n) {
                    float o = fmaxf(acc2[cc][r] + bv, 0.f);
                    if constexpr (OUT_BF16) {
                        ((unsigned short*)out)[(size_t)row * 128 + ncol] = f2bfu(o);
                    } else {
                        ((float*)out)[(size_t)row * 128 + ncol] = o;
                    }
                }
            }
        }
    }
}

extern "C" void kernel_launch(void* const* d_in, const int* in_sizes, int n_in,
                              void* d_out, int out_size, void* d_ws, size_t ws_size,
                              hipStream_t stream) {
    const int n = in_sizes[0] / 128;
    const int e = in_sizes[1] / 2;
    const void* x = d_in[0];
    const int* ei = (const int*)d_in[1];

    char* w = (char*)d_ws;
    size_t o = 0;
    auto alloc = [&](size_t bytes) -> char* {
        char* p = w + o;
        o += (bytes + 255) & ~(size_t)255;
        return p;
    };
    int* cnt   = (int*)alloc((size_t)n * 4);
    float* dinv = (float*)alloc((size_t)n * 4);
    int* slots = (int*)alloc((size_t)n * SLOTS * 4 + 64);  // +pad for prefetch tail
    unsigned short* W1h = (unsigned short*)alloc(16384 * 2);
    unsigned short* W1l = (unsigned short*)alloc(16384 * 2);
    unsigned short* W2h = (unsigned short*)alloc(16384 * 2);
    unsigned short* W2l = (unsigned short*)alloc(16384 * 2);
    float* bf1 = (float*)alloc(128 * 4);
    float* bf2 = (float*)alloc(128 * 4);
    unsigned int* Xb  = (unsigned int*)alloc((size_t)n * 64 * 4);  // layer-1 gather table
    unsigned int* Xb2 = (unsigned int*)alloc((size_t)n * 64 * 4);  // layer-2 gather table
    (void)ws_size;  // ~39 MB

    k_prep<<<1024, 256, 0, stream>>>(x, d_in[2], d_in[3], d_in[4], d_in[5],
                                     cnt, W1h, W1l, W2h, W2l, bf1, bf2, Xb, n);
    const int rpx = (n + 7) / 8;           // dst-range per XCD
    int ecx = ((e + 255) / 256) * 8;       // 8 range-blocks per edge chunk
    k_countfill<<<ecx, 256, 0, stream>>>(ei, cnt, slots, e, n, rpx);
    k_dinv<<<(n + 255) / 256, 256, 0, stream>>>(cnt, dinv, n);

    int gf = (n + 15) / 16;  // 3125 blocks x 4 waves = 12500 waves — keeps CUs saturated
    // layer 1: Xb2 = bf16(relu((dinv*agg(dinv*Xb)) @ W1 + b1))
    k_fused<true><<<gf, 256, 0, stream>>>(Xb, cnt, dinv, slots, W1h, W1l, bf1, Xb2, n);
    // layer 2: d_out = fp32(relu((dinv*agg(dinv*Xb2)) @ W2 + b2))
    k_fused<false><<<gf, 256, 0, stream>>>(Xb2, cnt, dinv, slots, W2h, W2l, bf2, d_out, n);
}